// Round 3
// baseline (3447.063 us; speedup 1.0000x reference)
//
#include <hip/hip_runtime.h>
#include <hip/hip_bf16.h>

#define N_  100000
#define E_  1200000
#define HH  64
#define EDIM 16
#define LL  3
#define GG  1000
#define CSTRIDE 9344   // A(4096) + B(4096) + C(1024) + c0(64) + d0(64)

__device__ __forceinline__ float rl(float v, int k) {
  return __uint_as_float(__builtin_amdgcn_readlane(__float_as_uint(v), k));
}

// ---------------- per-call precompute ----------------

__global__ void k_gcnt(const int* __restrict__ batch, float* __restrict__ gcnt) {
  for (int i = blockIdx.x * blockDim.x + threadIdx.x; i < N_; i += gridDim.x * blockDim.x)
    atomicAdd(&gcnt[batch[i]], 1.f);
}

// agg_ea[d][k] = sum of edge_attr over incoming edges; deg[d] = incoming edge count
__global__ void k_aea(const int* __restrict__ dst, const float* __restrict__ ea,
                      float* __restrict__ aea, float* __restrict__ deg) {
  int total = E_ * EDIM;
  for (int i = blockIdx.x * blockDim.x + threadIdx.x; i < total; i += gridDim.x * blockDim.x) {
    int e = i >> 4, k = i & 15;
    int d = dst[e];
    atomicAdd(&aea[d * EDIM + k], ea[i]);
    if (k == 0) atomicAdd(&deg[d], 1.f);
  }
}

// Fold layer constants: A = Wn@W1top, B = Wn@W1bot, C = We@W1bot,
// c0 = (bn+be)@W1bot, d0 = b1 + bn@W1top
__global__ void k_setup(const float* __restrict__ nodeW, const float* __restrict__ nodeB,
                        const float* __restrict__ edgeW, const float* __restrict__ edgeB,
                        const float* __restrict__ m1W, const float* __restrict__ m1B,
                        float* __restrict__ cst) {
  int l = blockIdx.x;
  __shared__ float sWn[4096], sWe[1024], sW1[8192];
  const float* Wn = nodeW + l * 4096;
  const float* We = edgeW + l * 1024;
  const float* W1 = m1W + l * 8192;
  for (int i = threadIdx.x; i < 4096; i += 256) sWn[i] = Wn[i];
  for (int i = threadIdx.x; i < 1024; i += 256) sWe[i] = We[i];
  for (int i = threadIdx.x; i < 8192; i += 256) sW1[i] = W1[i];
  __syncthreads();
  float* C = cst + l * CSTRIDE;
  int j = threadIdx.x & 63, q = threadIdx.x >> 6;
  for (int kk = 0; kk < 16; ++kk) {
    int k = q * 16 + kk;
    float a = 0.f, b = 0.f;
    for (int m = 0; m < 64; ++m) {
      float w = sWn[k * 64 + m];
      a += w * sW1[m * 64 + j];
      b += w * sW1[(64 + m) * 64 + j];
    }
    C[k * 64 + j] = a;
    C[4096 + k * 64 + j] = b;
  }
  if (q == 0) {
    for (int k = 0; k < 16; ++k) {
      float c = 0.f;
      for (int m = 0; m < 64; ++m) c += sWe[k * 64 + m] * sW1[(64 + m) * 64 + j];
      C[8192 + k * 64 + j] = c;
    }
  } else if (q == 1) {
    float c = 0.f;
    for (int m = 0; m < 64; ++m)
      c += (nodeB[l * 64 + m] + edgeB[l * 64 + m]) * sW1[(64 + m) * 64 + j];
    C[9216 + j] = c;
  } else if (q == 2) {
    float d = m1B[l * 64 + j];
    for (int m = 0; m < 64; ++m) d += nodeB[l * 64 + m] * sW1[m * 64 + j];
    C[9280 + j] = d;
  }
}

// ---------------- encoder: h = x @ encW + encB ----------------

__global__ void k_enc(const float* __restrict__ x, const float* __restrict__ W,
                      const float* __restrict__ b, float* __restrict__ out) {
  __shared__ float sW[4096];
  __shared__ float sb[64];
  for (int i = threadIdx.x; i < 4096; i += 256) sW[i] = W[i];
  if (threadIdx.x < 64) sb[threadIdx.x] = b[threadIdx.x];
  __syncthreads();
  int j = threadIdx.x & 63, w = threadIdx.x >> 6;
  int pairs = (N_ + 1) / 2;
  int gw = blockIdx.x * 4 + w, nwv = gridDim.x * 4;
  for (int p = gw; p < pairs; p += nwv) {
    int nA = p * 2, nB = nA + 1;
    float xA = x[nA * 64 + j];
    float xB = (nB < N_) ? x[nB * 64 + j] : 0.f;
    float aA = sb[j], aB = sb[j];
#pragma unroll
    for (int k = 0; k < 64; ++k) {
      float wv = sW[k * 64 + j];
      aA += rl(xA, k) * wv;
      aB += rl(xB, k) * wv;
    }
    out[nA * 64 + j] = aA;
    if (nB < N_) out[nB * 64 + j] = aB;
  }
}

// ---------------- per-layer: edge scatter ah[d] += h[s] ----------------

__global__ void k_edge(const float* __restrict__ h, const int* __restrict__ src,
                       const int* __restrict__ dst, float* __restrict__ ah) {
  int lane = threadIdx.x & 63;
  int gw = blockIdx.x * (blockDim.x >> 6) + (threadIdx.x >> 6);
  int nwv = gridDim.x * (blockDim.x >> 6);
  for (int base = gw * 4; base < E_; base += nwv * 4) {
    // E_ % 4 == 0 so the full quad is always valid
    int s0 = src[base + 0], d0 = dst[base + 0];
    int s1 = src[base + 1], d1 = dst[base + 1];
    int s2 = src[base + 2], d2 = dst[base + 2];
    int s3 = src[base + 3], d3 = dst[base + 3];
    float v0 = h[s0 * 64 + lane];
    float v1 = h[s1 * 64 + lane];
    float v2 = h[s2 * 64 + lane];
    float v3 = h[s3 * 64 + lane];
    atomicAdd(&ah[d0 * 64 + lane], v0);
    atomicAdd(&ah[d1 * 64 + lane], v1);
    atomicAdd(&ah[d2 * 64 + lane], v2);
    atomicAdd(&ah[d3 * 64 + lane], v3);
  }
}

// ---------------- per-layer: fused node MLP + graph-sum partials ----------------

__global__ void k_node(const float* __restrict__ h, const float* __restrict__ ah,
                       const float* __restrict__ aea, const float* __restrict__ deg,
                       const int* __restrict__ batch,
                       const float* __restrict__ cst,   // this layer's A,B,C,c0,d0
                       const float* __restrict__ W2, const float* __restrict__ b2,
                       float* __restrict__ h2, float* __restrict__ gsum,
                       float* __restrict__ gsqs) {
  __shared__ float sA[4096], sB[4096], sW2[4096], sC[1024];
  __shared__ float sc0[64], sd0[64], sb2[64];
  for (int i = threadIdx.x; i < 4096; i += 256) {
    sA[i] = cst[i];
    sB[i] = cst[4096 + i];
    sW2[i] = W2[i];
  }
  for (int i = threadIdx.x; i < 1024; i += 256) sC[i] = cst[8192 + i];
  if (threadIdx.x < 64) {
    sc0[threadIdx.x] = cst[9216 + threadIdx.x];
    sd0[threadIdx.x] = cst[9280 + threadIdx.x];
    sb2[threadIdx.x] = b2[threadIdx.x];
  }
  __syncthreads();
  int j = threadIdx.x & 63, w = threadIdx.x >> 6;
  int chunk = (((N_ + gridDim.x - 1) / gridDim.x) + 7) & ~7;  // contiguous rows per block
  int base = blockIdx.x * chunk;
  float gacc = 0.f, gacc2 = 0.f;
  int gcur = -1;
  for (int it = 0; it < chunk; it += 8) {
    int nA = base + it + w * 2;
    int nB = nA + 1;
    bool vA = nA < N_, vB = nB < N_;
    float xA = 0.f, xB = 0.f, yA = 0.f, yB = 0.f, eA = 0.f, eB = 0.f, dgA = 0.f, dgB = 0.f;
    if (vA) {
      xA = h[nA * 64 + j];
      yA = ah[nA * 64 + j];
      if (j < 16) eA = aea[nA * 16 + j];
      dgA = deg[nA];
    }
    if (vB) {
      xB = h[nB * 64 + j];
      yB = ah[nB * 64 + j];
      if (j < 16) eB = aea[nB * 16 + j];
      dgB = deg[nB];
    }
    float accA = sd0[j] + dgA * sc0[j];
    float accB = sd0[j] + dgB * sc0[j];
#pragma unroll
    for (int k = 0; k < 64; ++k) {
      float wv = sA[k * 64 + j];
      accA += rl(xA, k) * wv;
      accB += rl(xB, k) * wv;
    }
#pragma unroll
    for (int k = 0; k < 64; ++k) {
      float wv = sB[k * 64 + j];
      accA += rl(yA, k) * wv;
      accB += rl(yB, k) * wv;
    }
#pragma unroll
    for (int k = 0; k < 16; ++k) {
      float wv = sC[k * 64 + j];
      accA += rl(eA, k) * wv;
      accB += rl(eB, k) * wv;
    }
    float tA = fmaxf(accA, 0.f), tB = fmaxf(accB, 0.f);
    float oA = sb2[j], oB = sb2[j];
#pragma unroll
    for (int k = 0; k < 64; ++k) {
      float wv = sW2[k * 64 + j];
      oA += rl(tA, k) * wv;
      oB += rl(tB, k) * wv;
    }
    if (vA) {
      h2[nA * 64 + j] = oA;
      int g = batch[nA];
      if (g != gcur) {
        if (gcur >= 0) {
          atomicAdd(&gsum[gcur * 64 + j], gacc);
          atomicAdd(&gsqs[gcur * 64 + j], gacc2);
        }
        gcur = g; gacc = 0.f; gacc2 = 0.f;
      }
      gacc += oA; gacc2 += oA * oA;
    }
    if (vB) {
      h2[nB * 64 + j] = oB;
      int g = batch[nB];
      if (g != gcur) {
        if (gcur >= 0) {
          atomicAdd(&gsum[gcur * 64 + j], gacc);
          atomicAdd(&gsqs[gcur * 64 + j], gacc2);
        }
        gcur = g; gacc = 0.f; gacc2 = 0.f;
      }
      gacc += oB; gacc2 += oB * oB;
    }
  }
  if (gcur >= 0) {
    atomicAdd(&gsum[gcur * 64 + j], gacc);
    atomicAdd(&gsqs[gcur * 64 + j], gacc2);
  }
}

// ---------------- per-layer: graph-norm + relu + residual ----------------

__global__ void k_fin(const float* __restrict__ h2, const int* __restrict__ batch,
                      const float* __restrict__ gsum, const float* __restrict__ gsqs,
                      const float* __restrict__ gcnt, const float* __restrict__ nw_,
                      const float* __restrict__ nb_, float* __restrict__ h) {
  int total = N_ * 64;
  for (int i = blockIdx.x * blockDim.x + threadIdx.x; i < total; i += gridDim.x * blockDim.x) {
    int n = i >> 6, j = i & 63;
    int g = batch[n];
    float c = fmaxf(gcnt[g], 1.f);
    float m = gsum[g * 64 + j] / c;
    float m2 = gsqs[g * 64 + j] / c;
    float var = m2 - m * m;
    float val = nw_[j] * (h2[i] - m) * rsqrtf(var + 1e-5f) + nb_[j];
    val = fmaxf(val, 0.f);
    h[i] = val + h[i];
  }
}

// ---------------- launch ----------------

extern "C" void kernel_launch(void* const* d_in, const int* in_sizes, int n_in,
                              void* d_out, int out_size, void* d_ws, size_t ws_size,
                              hipStream_t stream) {
  const float* x     = (const float*)d_in[0];
  const int*   eidx  = (const int*)d_in[1];
  const float* eattr = (const float*)d_in[2];
  const int*   batch = (const int*)d_in[3];
  const float* encW  = (const float*)d_in[4];
  const float* encB  = (const float*)d_in[5];
  const float* nodeW = (const float*)d_in[6];
  const float* nodeB = (const float*)d_in[7];
  const float* edgeW = (const float*)d_in[8];
  const float* edgeB = (const float*)d_in[9];
  const float* m1W   = (const float*)d_in[10];
  const float* m1B   = (const float*)d_in[11];
  const float* m2W   = (const float*)d_in[12];
  const float* m2B   = (const float*)d_in[13];
  const float* nw    = (const float*)d_in[14];
  const float* nb    = (const float*)d_in[15];

  float* h  = (float*)d_out;
  float* ws = (float*)d_ws;
  float* ah   = ws;                      // N*64
  float* h2   = ah + N_ * 64;            // N*64
  float* aea  = h2 + N_ * 64;            // N*16
  float* deg  = aea + N_ * EDIM;         // N
  float* gsum = deg + N_;                // G*64
  float* gsqs = gsum + GG * 64;          // G*64
  float* gcnt = gsqs + GG * 64;          // G
  float* cst  = gcnt + GG;               // 3*CSTRIDE

  const int* srcI = eidx;
  const int* dstI = eidx + E_;

  // zero once-per-call accumulators (aea and deg are contiguous)
  hipMemsetAsync(aea, 0, (size_t)(N_ * EDIM + N_) * 4, stream);
  hipMemsetAsync(gcnt, 0, GG * 4, stream);

  k_gcnt<<<512, 256, 0, stream>>>(batch, gcnt);
  k_aea<<<2048, 256, 0, stream>>>(dstI, eattr, aea, deg);
  k_setup<<<3, 256, 0, stream>>>(nodeW, nodeB, edgeW, edgeB, m1W, m1B, cst);
  k_enc<<<1024, 256, 0, stream>>>(x, encW, encB, h);

  for (int l = 0; l < LL; ++l) {
    hipMemsetAsync(ah, 0, (size_t)N_ * 64 * 4, stream);
    hipMemsetAsync(gsum, 0, (size_t)GG * 64 * 2 * 4, stream);
    k_edge<<<1024, 256, 0, stream>>>(h, srcI, dstI, ah);
    k_node<<<1024, 256, 0, stream>>>(h, ah, aea, deg, batch, cst + l * CSTRIDE,
                                     m2W + l * 4096, m2B + l * 64, h2, gsum, gsqs);
    k_fin<<<2048, 256, 0, stream>>>(h2, batch, gsum, gsqs, gcnt,
                                    nw + l * 64, nb + l * 64, h);
  }
}